// Round 8
// baseline (229.533 us; speedup 1.0000x reference)
//
#include <hip/hip_runtime.h>

// Problem constants (B,C,H,W)=(32,64,64,64), code_size=512
#define HWDIM 4096
#define CDIM  64
#define KDIM  512
#define ST_ELEMS   8388608   // 32*64*64*64
#define LOSS_OFF   8519680   // ST_ELEMS + 32*64*64

// R13: fp16-dot2 prune + sound exact rescan (algorithm validated R9-R12),
// with ZERO LDS in the hot loop. R12's lesson: per-scope ds_read of the
// invariant x-fragment (1024 reads/thread, 6.29M bank conflicts) + the
// shared lgkmcnt (SMEM is out-of-order -> lgkmcnt(0) per scope drains the
// LDS queue too) serialized the PASS. Fix:
//  - fp16 x (xhA/xhB, 64 u32) packed ONCE directly from the pinned fp32
//    registers; lives in VGPRs for the whole PASS.
//  - sc streamed through the SCALAR pipe (s_load_dwordx4 per 4-row group,
//    fused with the codebook stream); rescan reads sc per-lane from L2.
//  - PASS granularity = R8's proven 4-row group: 8x s_load_dwordx16 +
//    256 dot2 (32 MACs per scalar load), half of R8's bytes AND issue.
//  - fp32 x/y stay PINNED in 128 regs (R12-proven: parked in the unified
//    RF, zero scratch); rescan + epilogue read pinned regs, no reloads.
//  - MARGIN=6e-4 soundly covers fp16 error (validated R9-R12, identical
//    arithmetic); exact rescan recomputes R8's bit-identical fmaf chain +
//    e-formula; packed-u64 min reproduces first-min tie-break exactly.

#define MARGIN 6e-4f

#define REP64(M) M(0) M(1) M(2) M(3) M(4) M(5) M(6) M(7) M(8) M(9) \
  M(10) M(11) M(12) M(13) M(14) M(15) M(16) M(17) M(18) M(19) \
  M(20) M(21) M(22) M(23) M(24) M(25) M(26) M(27) M(28) M(29) \
  M(30) M(31) M(32) M(33) M(34) M(35) M(36) M(37) M(38) M(39) \
  M(40) M(41) M(42) M(43) M(44) M(45) M(46) M(47) M(48) M(49) \
  M(50) M(51) M(52) M(53) M(54) M(55) M(56) M(57) M(58) M(59) \
  M(60) M(61) M(62) M(63)

typedef unsigned int uint;
typedef _Float16 half2_t __attribute__((ext_vector_type(2)));
typedef uint uv16 __attribute__((ext_vector_type(16)));
typedef float vf4 __attribute__((ext_vector_type(4)));
typedef __attribute__((address_space(4))) const uv16 cuv16;
typedef __attribute__((address_space(4))) const vf4 cvf4;

// numpy fp32 pairwise sum-of-squares of 64 contiguous values — bit-validated.
__device__ __forceinline__ float np_sumsq64(const float a[64]) {
#pragma clang fp contract(off)
  float v[16];
#pragma unroll
  for (int i = 0; i < 16; ++i) {
    float s0 = a[i]      * a[i];
    float s1 = a[i + 16] * a[i + 16];
    float s2 = a[i + 32] * a[i + 32];
    float s3 = a[i + 48] * a[i + 48];
    v[i] = (s0 + s1) + (s2 + s3);
  }
  float t0 = (v[0] + v[8])  + (v[4] + v[12]);
  float t1 = (v[1] + v[9])  + (v[5] + v[13]);
  float t2 = (v[2] + v[10]) + (v[6] + v[14]);
  float t3 = (v[3] + v[11]) + (v[7] + v[15]);
  return (t0 + t2) + (t1 + t3);
}

// Pack two floats as half2-in-u32 (RNE via _Float16 cast; low half = first).
__device__ __forceinline__ uint pkh(float lo, float hi) {
  unsigned short l = __builtin_bit_cast(unsigned short, (_Float16)lo);
  unsigned short h = __builtin_bit_cast(unsigned short, (_Float16)hi);
  return ((uint)h << 16) | (uint)l;
}

#if __has_builtin(__builtin_amdgcn_fdot2)
#define DOT(acc, xu, cu) acc = __builtin_amdgcn_fdot2( \
    __builtin_bit_cast(half2_t, (uint)(xu)), \
    __builtin_bit_cast(half2_t, (uint)(cu)), acc, false);
#else
#define DOT(acc, xu, cu) { half2_t xa_ = __builtin_bit_cast(half2_t, (uint)(xu)); \
    half2_t cb_ = __builtin_bit_cast(half2_t, (uint)(cu)); \
    acc = __builtin_fmaf((float)xa_.y, (float)cb_.y, \
          __builtin_fmaf((float)xa_.x, (float)cb_.x, acc)); }
#endif

// ---------------- pre-kernel: sc[512] + half2 codebook*256 into ws ---------
__global__ void vq_pre(const float* __restrict__ cb, uint* __restrict__ ws) {
  int k = blockIdx.x * 256 + threadIdx.x;
  if (k < KDIM) {
    float row[64];
#pragma unroll
    for (int c = 0; c < 64; ++c) row[c] = cb[(k << 6) + c];
    ((float*)ws)[k] = np_sumsq64(row);
    uint* dst = ws + 512 + k * 32;
#pragma unroll
    for (int j = 0; j < 32; ++j)
      dst[j] = pkh(row[2 * j] * 256.f, row[2 * j + 1] * 256.f);
  }
}

// fp32 regs -> 32 packed fp16 pairs (ascending channel order).
#define PK32(XH, V) \
  XH[0]=pkh(V##0,V##1);    XH[1]=pkh(V##2,V##3);    XH[2]=pkh(V##4,V##5);    XH[3]=pkh(V##6,V##7); \
  XH[4]=pkh(V##8,V##9);    XH[5]=pkh(V##10,V##11);  XH[6]=pkh(V##12,V##13);  XH[7]=pkh(V##14,V##15); \
  XH[8]=pkh(V##16,V##17);  XH[9]=pkh(V##18,V##19);  XH[10]=pkh(V##20,V##21); XH[11]=pkh(V##22,V##23); \
  XH[12]=pkh(V##24,V##25); XH[13]=pkh(V##26,V##27); XH[14]=pkh(V##28,V##29); XH[15]=pkh(V##30,V##31); \
  XH[16]=pkh(V##32,V##33); XH[17]=pkh(V##34,V##35); XH[18]=pkh(V##36,V##37); XH[19]=pkh(V##38,V##39); \
  XH[20]=pkh(V##40,V##41); XH[21]=pkh(V##42,V##43); XH[22]=pkh(V##44,V##45); XH[23]=pkh(V##46,V##47); \
  XH[24]=pkh(V##48,V##49); XH[25]=pkh(V##50,V##51); XH[26]=pkh(V##52,V##53); XH[27]=pkh(V##54,V##55); \
  XH[28]=pkh(V##56,V##57); XH[29]=pkh(V##58,V##59); XH[30]=pkh(V##60,V##61); XH[31]=pkh(V##62,V##63);

// ---------------- main kernel ----------------------------------------------
__global__ __launch_bounds__(256)
__attribute__((amdgpu_waves_per_eu(2, 2)))
void vq_kernel(
    const float* __restrict__ x, const float* __restrict__ cb,
    const uint* __restrict__ ws,
    float* __restrict__ st, float* __restrict__ idxo, float* __restrict__ loss)
{
  __shared__ unsigned long long mrg[256];
  __shared__ float lred[4];

  const int tid = threadIdx.x;
  const int pix = tid & 127;                       // pixel-pair slot
  // tid>>7 IS wave-uniform (64-thread waves don't straddle 128) — force SGPR.
  const int khalf = __builtin_amdgcn_readfirstlane(tid >> 7);
  const int b   = blockIdx.x & 31;
  const int p   = ((blockIdx.x >> 5) << 8) + pix;  // px A; px B = p+128

  // Constant-AS views: packed fp16 codebook (64B chunks) and sc (16B chunks)
  // — wave-uniform addresses -> s_load_dwordx16 / s_load_dwordx4 scalar
  // streaming. Row = 2 chunks = 128B.
  cuv16* cw  = (cuv16*)(uintptr_t)(ws + 512);
  cvf4*  scw = (cvf4*)(uintptr_t)ws;
  const float* scg = (const float*)ws;             // per-lane sc for rescan

  const float* xpA = x + (size_t)b * (CDIM * HWDIM) + p;
  const float* xpB = xpA + 128;

  // Load BOTH pixels' points into 128 named, pinned registers (R8 pattern).
#define XLOAD(i) float x##i = xpA[(i) * HWDIM]; asm("" : "+v"(x##i));
#define YLOAD(i) float y##i = xpB[(i) * HWDIM]; asm("" : "+v"(y##i));
  REP64(XLOAD)
  REP64(YLOAD)
#undef XLOAD
#undef YLOAD

  // Exact S per pixel — R8's bit-identical numpy pairwise tree.
#define SQT(V, i, j, k2, l) \
    float v##i = ((V##i * V##i) + (V##j * V##j)) + ((V##k2 * V##k2) + (V##l * V##l));
#define SUMSQ_TREE(V, OUT) { \
    _Pragma("clang fp contract(off)") \
    SQT(V,0,16,32,48) SQT(V,1,17,33,49) SQT(V,2,18,34,50) SQT(V,3,19,35,51) \
    SQT(V,4,20,36,52) SQT(V,5,21,37,53) SQT(V,6,22,38,54) SQT(V,7,23,39,55) \
    SQT(V,8,24,40,56) SQT(V,9,25,41,57) SQT(V,10,26,42,58) SQT(V,11,27,43,59) \
    SQT(V,12,28,44,60) SQT(V,13,29,45,61) SQT(V,14,30,46,62) SQT(V,15,31,47,63) \
    float t0 = (v0 + v8)  + (v4 + v12); \
    float t1 = (v1 + v9)  + (v5 + v13); \
    float t2 = (v2 + v10) + (v6 + v14); \
    float t3 = (v3 + v11) + (v7 + v15); \
    OUT = (t0 + t2) + (t1 + t3); }

  float S_A, S_B;
  SUMSQ_TREE(x, S_A)
  SUMSQ_TREE(y, S_B)
#undef SUMSQ_TREE
#undef SQT

  // fp16 x copies in VGPRs, packed once from the pinned regs. No LDS.
  uint xhA[32], xhB[32];
  PK32(xhA, x)
  PK32(xhB, y)

  // ---- PASS: fp16 dot2 over this half's 256 codes; candidate bitmasks
  // (f < runmin + MARGIN). c scaled by 256 -> f = sc - 2*d/256 -> -0.0078125.
  const int qbase = khalf << 8;
  float runA = __builtin_inff(), runB = __builtin_inff();
  uint mA0 = 0, mA1 = 0, mA2 = 0, mA3 = 0, mA4 = 0, mA5 = 0, mA6 = 0, mA7 = 0;
  uint mB0 = 0, mB1 = 0, mB2 = 0, mB3 = 0, mB4 = 0, mB5 = 0, mB6 = 0, mB7 = 0;

  // Two scopes of 4 live uv16 (64 SGPR peak — R8's proven chunk schedule).
#define PASSJ(J, MA, MB) \
  for (int g = 0; g < 8; ++g) { \
    const int krow = qbase + ((J) << 5) + (g << 2); \
    const int rb = krow << 1;   /* row k = chunks 2k, 2k+1 */ \
    vf4 sq = scw[krow >> 2];    /* sc[k..k+3] via scalar pipe */ \
    float d0a = 0.f, d1a = 0.f, d2a = 0.f, d3a = 0.f; \
    float d0b = 0.f, d1b = 0.f, d2b = 0.f, d3b = 0.f; \
    {  /* channels 0..31 of rows krow..krow+3 */ \
      uv16 q0 = cw[rb], q1 = cw[rb + 2], q2 = cw[rb + 4], q3 = cw[rb + 6]; \
      _Pragma("unroll") \
      for (int t = 0; t < 16; ++t) { \
        DOT(d0a, xhA[t], q0[t]) DOT(d0b, xhB[t], q0[t]) \
        DOT(d1a, xhA[t], q1[t]) DOT(d1b, xhB[t], q1[t]) \
        DOT(d2a, xhA[t], q2[t]) DOT(d2b, xhB[t], q2[t]) \
        DOT(d3a, xhA[t], q3[t]) DOT(d3b, xhB[t], q3[t]) \
      } \
    } \
    {  /* channels 32..63 of rows krow..krow+3 */ \
      uv16 q0 = cw[rb + 1], q1 = cw[rb + 3], q2 = cw[rb + 5], q3 = cw[rb + 7]; \
      _Pragma("unroll") \
      for (int t = 0; t < 16; ++t) { \
        DOT(d0a, xhA[16 + t], q0[t]) DOT(d0b, xhB[16 + t], q0[t]) \
        DOT(d1a, xhA[16 + t], q1[t]) DOT(d1b, xhB[16 + t], q1[t]) \
        DOT(d2a, xhA[16 + t], q2[t]) DOT(d2b, xhB[16 + t], q2[t]) \
        DOT(d3a, xhA[16 + t], q3[t]) DOT(d3b, xhB[16 + t], q3[t]) \
      } \
    } \
    float f0a = __builtin_fmaf(-0.0078125f, d0a, sq.x); \
    float f1a = __builtin_fmaf(-0.0078125f, d1a, sq.y); \
    float f2a = __builtin_fmaf(-0.0078125f, d2a, sq.z); \
    float f3a = __builtin_fmaf(-0.0078125f, d3a, sq.w); \
    float f0b = __builtin_fmaf(-0.0078125f, d0b, sq.x); \
    float f1b = __builtin_fmaf(-0.0078125f, d1b, sq.y); \
    float f2b = __builtin_fmaf(-0.0078125f, d2b, sq.z); \
    float f3b = __builtin_fmaf(-0.0078125f, d3b, sq.w); \
    const float thA = runA + MARGIN, thB = runB + MARGIN; \
    const uint bit0 = 1u << (g << 2); \
    MA |= (f0a < thA ? bit0 : 0u) | (f1a < thA ? (bit0 << 1) : 0u) \
        | (f2a < thA ? (bit0 << 2) : 0u) | (f3a < thA ? (bit0 << 3) : 0u); \
    MB |= (f0b < thB ? bit0 : 0u) | (f1b < thB ? (bit0 << 1) : 0u) \
        | (f2b < thB ? (bit0 << 2) : 0u) | (f3b < thB ? (bit0 << 3) : 0u); \
    runA = fminf(runA, fminf(fminf(f0a, f1a), fminf(f2a, f3a))); \
    runB = fminf(runB, fminf(fminf(f0b, f1b), fminf(f2b, f3b))); \
  }
  PASSJ(0, mA0, mB0)
  PASSJ(1, mA1, mB1)
  PASSJ(2, mA2, mB2)
  PASSJ(3, mA3, mB3)
  PASSJ(4, mA4, mB4)
  PASSJ(5, mA5, mB5)
  PASSJ(6, mA6, mB6)
  PASSJ(7, mA7, mB7)
#undef PASSJ

  // ---- Exact rescan of candidates using the PINNED fp32 regs (no reloads).
  // Bit-identical R8 fmaf chain (ascending c) + e-formula.
#define FQ(d, R, V, A0, A1, A2, A3) \
    d = __builtin_fmaf(V##A0, R.x, d); d = __builtin_fmaf(V##A1, R.y, d); \
    d = __builtin_fmaf(V##A2, R.z, d); d = __builtin_fmaf(V##A3, R.w, d);
#define RESROW(d, rw, V) \
    { float4 r0 = rw[0], r1 = rw[1], r2 = rw[2], r3 = rw[3]; \
      FQ(d, r0, V, 0, 1, 2, 3)      FQ(d, r1, V, 4, 5, 6, 7) \
      FQ(d, r2, V, 8, 9, 10, 11)    FQ(d, r3, V, 12, 13, 14, 15) \
      r0 = rw[4]; r1 = rw[5]; r2 = rw[6]; r3 = rw[7]; \
      FQ(d, r0, V, 16, 17, 18, 19)  FQ(d, r1, V, 20, 21, 22, 23) \
      FQ(d, r2, V, 24, 25, 26, 27)  FQ(d, r3, V, 28, 29, 30, 31) \
      r0 = rw[8]; r1 = rw[9]; r2 = rw[10]; r3 = rw[11]; \
      FQ(d, r0, V, 32, 33, 34, 35)  FQ(d, r1, V, 36, 37, 38, 39) \
      FQ(d, r2, V, 40, 41, 42, 43)  FQ(d, r3, V, 44, 45, 46, 47) \
      r0 = rw[12]; r1 = rw[13]; r2 = rw[14]; r3 = rw[15]; \
      FQ(d, r0, V, 48, 49, 50, 51)  FQ(d, r1, V, 52, 53, 54, 55) \
      FQ(d, r2, V, 56, 57, 58, 59)  FQ(d, r3, V, 60, 61, 62, 63) }

#define RES1(MM, J, SS, PK, V) \
    { uint m_ = MM; \
      while (__any(m_ != 0u)) { \
        if (m_ != 0u) { \
          const int kk = qbase + ((J) << 5) + (__ffs(m_) - 1); \
          const float4* rw = (const float4*)(cb + ((size_t)kk << 6)); \
          float d = 0.f; \
          RESROW(d, rw, V) \
          float e; \
          { _Pragma("clang fp contract(off)") e = (SS - (d + d)) + scg[kk]; } \
          unsigned long long c_ = \
              ((unsigned long long)__float_as_uint(e) << 32) | (uint)kk; \
          if (c_ < PK) PK = c_; \
          m_ &= m_ - 1u; \
        } \
      } }

  unsigned long long pkA = ~0ull, pkB = ~0ull;
  RES1(mA0, 0, S_A, pkA, x) RES1(mA1, 1, S_A, pkA, x)
  RES1(mA2, 2, S_A, pkA, x) RES1(mA3, 3, S_A, pkA, x)
  RES1(mA4, 4, S_A, pkA, x) RES1(mA5, 5, S_A, pkA, x)
  RES1(mA6, 6, S_A, pkA, x) RES1(mA7, 7, S_A, pkA, x)
  RES1(mB0, 0, S_B, pkB, y) RES1(mB1, 1, S_B, pkB, y)
  RES1(mB2, 2, S_B, pkB, y) RES1(mB3, 3, S_B, pkB, y)
  RES1(mB4, 4, S_B, pkB, y) RES1(mB5, 5, S_B, pkB, y)
  RES1(mB6, 6, S_B, pkB, y) RES1(mB7, 7, S_B, pkB, y)
#undef RES1
#undef RESROW
#undef FQ

  // ---- Cross-half exact merge (u64 min == first-min semantics: distances
  // positive -> fp32 bits order identically; idx in low word).
  if (khalf) { mrg[pix] = pkA; mrg[pix + 128] = pkB; }
  __syncthreads();

  float lsum = 0.f;
  if (!khalf) {
    { unsigned long long o = mrg[pix];       if (o < pkA) pkA = o; }
    { unsigned long long o = mrg[pix + 128]; if (o < pkB) pkB = o; }
    const int bestiA = (int)(pkA & 0xffffffffull);
    const int bestiB = (int)(pkB & 0xffffffffull);

    // Epilogue from PINNED regs — identical to R8 (no reloads).
    const float* crowA = cb + (bestiA << 6);
    const float* crowB = cb + (bestiB << 6);
    float* stpA = st + (size_t)b * (CDIM * HWDIM) + p;
    float* stpB = stpA + 128;
    float lsumA = 0.f, lsumB = 0.f;
#define EPIA(i) { float cv = crowA[i]; float df; \
    { _Pragma("clang fp contract(off)") df = cv - x##i; } \
    lsumA = __builtin_fmaf(df, df, lsumA); stpA[(i) * HWDIM] = cv; }
#define EPIB(i) { float cv = crowB[i]; float df; \
    { _Pragma("clang fp contract(off)") df = cv - y##i; } \
    lsumB = __builtin_fmaf(df, df, lsumB); stpB[(i) * HWDIM] = cv; }
    REP64(EPIA)
    REP64(EPIB)
#undef EPIA
#undef EPIB

    idxo[b * HWDIM + p]       = (float)bestiA;
    idxo[b * HWDIM + p + 128] = (float)bestiB;
    lsum = lsumA + lsumB;
  }

  // Block reduce loss, one atomic per block (R8's exact tree; waves 2-3
  // contribute exact zeros, t + 0.0f == t bitwise for nonnegative sums).
#pragma unroll
  for (int off = 32; off > 0; off >>= 1) lsum += __shfl_down(lsum, off);
  if ((tid & 63) == 0) lred[tid >> 6] = lsum;
  __syncthreads();
  if (tid == 0) {
    float t = (lred[0] + lred[1]) + (lred[2] + lred[3]);
    atomicAdd(loss, t * (1.25f / 8388608.f));
  }
}

extern "C" void kernel_launch(void* const* d_in, const int* in_sizes, int n_in,
                              void* d_out, int out_size, void* d_ws, size_t ws_size,
                              hipStream_t stream) {
  const float* x  = (const float*)d_in[0];   // (32,64,64,64) fp32
  const float* cb = (const float*)d_in[1];   // (512,64) fp32
  float* st   = (float*)d_out;               // (32,64,64,64)
  float* idxo = (float*)d_out + ST_ELEMS;    // (32,64,64) as float
  float* loss = (float*)d_out + LOSS_OFF;    // scalar
  uint*  ws   = (uint*)d_ws;                 // 2KB sc + 64KB half2 codebook

  hipMemsetAsync(loss, 0, sizeof(float), stream);  // d_out is poisoned each call
  vq_pre<<<dim3(2), dim3(256), 0, stream>>>(cb, ws);
  vq_kernel<<<dim3(512), dim3(256), 0, stream>>>(x, cb, ws, st, idxo, loss);
}